// Round 1
// baseline (266.449 us; speedup 1.0000x reference)
//
#include <hip/hip_runtime.h>
#include <hip/hip_bf16.h>

// Problem constants (fixed by setup_inputs):
//   B=32, T=1024, N=1024, R=8, C=32, NPR=128, RKEEP=6, HID=1024, NLAT=160
// out[b,t,l] = sum_{r in ids_shuffle[b,0:6]} sum_n spikes[b,t,r*128+n]*F[l,r*128+n]
//              + bias0[l] + sum_{r active} bias_area[l,r]
// F = (V_W@U_W) folded with W_area; computed on device each launch (no state).

typedef float f32x4 __attribute__((ext_vector_type(4)));
typedef __bf16 bf16x8 __attribute__((ext_vector_type(8)));

// ---------------- P_A: M partials = V_W (160x1024) @ U_W (1024x256), K-split 4
// grid 160 = 40 l-quads x 4 k-chunks; M_part[ck][l][rc] fp32
__global__ __launch_bounds__(256) void pa_kernel(const float* __restrict__ V_W,
                                                 const float* __restrict__ U_W,
                                                 float* __restrict__ M_part) {
    const int rc = threadIdx.x;
    const int lq = blockIdx.x >> 2;   // 0..39
    const int ck = blockIdx.x & 3;    // 0..3
    const int l0 = lq * 4;
    const int h0 = ck * 256;
    float a0 = 0.f, a1 = 0.f, a2 = 0.f, a3 = 0.f;
#pragma unroll 4
    for (int hh = 0; hh < 256; ++hh) {
        const int h = h0 + hh;
        const float u = U_W[h * 256 + rc];          // coalesced, L2-hot
        a0 += V_W[(l0 + 0) * 1024 + h] * u;         // uniform -> s_loads
        a1 += V_W[(l0 + 1) * 1024 + h] * u;
        a2 += V_W[(l0 + 2) * 1024 + h] * u;
        a3 += V_W[(l0 + 3) * 1024 + h] * u;
    }
    float* dst = M_part + (size_t)ck * 160 * 256;
    dst[(l0 + 0) * 256 + rc] = a0;
    dst[(l0 + 1) * 256 + rc] = a1;
    dst[(l0 + 2) * 256 + rc] = a2;
    dst[(l0 + 3) * 256 + rc] = a3;
}

// ---------------- P_B: per-l row: reduce M partials, fold with W_area -> F(bf16),
// bias_area[l][r], bias0[l]. grid 160 (one block per l), 256 threads.
__global__ __launch_bounds__(256) void pb_kernel(const float* __restrict__ M_part,
                                                 const float* __restrict__ W_area,
                                                 const float* __restrict__ b_area,
                                                 const float* __restrict__ V_W,
                                                 const float* __restrict__ U_b,
                                                 const float* __restrict__ V_b,
                                                 __bf16* __restrict__ F,
                                                 float* __restrict__ bias_area,
                                                 float* __restrict__ bias0) {
    const int l = blockIdx.x;
    const int tid = threadIdx.x;
    __shared__ float Mrow[256];
    __shared__ float red[256];

    // phase 0: sum the 4 K-split partials -> final M row (256 floats)
    float m = 0.f;
#pragma unroll
    for (int p = 0; p < 4; ++p) m += M_part[(size_t)(p * 160 + l) * 256 + tid];
    Mrow[tid] = m;

    // bias0 partial: V_W[l,:] . U_b  (U_b is zeros in this problem, keep for safety)
    float p0 = 0.f;
#pragma unroll
    for (int hh = 0; hh < 4; ++hh) {
        const int h = tid + hh * 256;
        p0 += V_W[(size_t)l * 1024 + h] * U_b[h];
    }
    red[tid] = p0;
    __syncthreads();

    // phase 1: F[l][r*128+n] = sum_c Mrow[r*32+c] * W_area[r,c,n]
#pragma unroll
    for (int p = 0; p < 4; ++p) {
        const int rn = tid + p * 256;
        const int r = rn >> 7, n = rn & 127;
        float acc = 0.f;
#pragma unroll 8
        for (int c = 0; c < 32; ++c)
            acc += Mrow[r * 32 + c] * W_area[((r * 32 + c) << 7) + n];
        F[(size_t)l * 1024 + rn] = (__bf16)acc;
    }

    // phase 2: bias_area[l][r] = sum_c Mrow[r*32+c] * b_area[r,c]
    if (tid < 8) {
        const int r = tid;
        float acc = 0.f;
        for (int c = 0; c < 32; ++c) acc += Mrow[r * 32 + c] * b_area[r * 32 + c];
        bias_area[l * 8 + r] = acc;
    }

    // phase 3: reduce bias0 partials
    for (int off = 128; off > 0; off >>= 1) {
        __syncthreads();
        if (tid < off) red[tid] += red[tid + off];
    }
    if (tid == 0) bias0[l] = V_b[l] + red[0];
}

// ---------------- MAIN: fused masked GEMM.
// grid 256 blocks (1/CU), 256 threads = 4 waves. Block = 128 tokens (within one
// batch: 8 blocks/batch), wave = 32 tokens (2 M-tiles). 10 N-tiles cover NLAT=160.
// K-loop: 6 active regions x 4 K-steps of 32 (skips masked regions entirely).
__global__ __launch_bounds__(256, 1) void main_kernel(const float* __restrict__ spikes,
                                                      const int* __restrict__ ids,
                                                      const __bf16* __restrict__ F,
                                                      const float* __restrict__ bias_area,
                                                      const float* __restrict__ bias0,
                                                      float* __restrict__ out) {
    const int tid = threadIdx.x;
    const int lane = tid & 63;
    const int wave = tid >> 6;
    const int s = lane & 15;   // A: m index / B: n index / D: col
    const int q = lane >> 4;   // K quad
    const int blk = blockIdx.x;
    const int b = blk >> 3;                 // batch (128 tokens/block, 1024/batch)
    const int tok0 = blk * 128 + wave * 32; // wave's first token

    int rj[6];
#pragma unroll
    for (int j = 0; j < 6; ++j) rj[j] = ids[b * 8 + j];  // active regions (uniform)

    f32x4 acc[2][10];
#pragma unroll
    for (int mt = 0; mt < 2; ++mt)
#pragma unroll
        for (int nt = 0; nt < 10; ++nt) acc[mt][nt] = (f32x4){0.f, 0.f, 0.f, 0.f};

#pragma unroll 1
    for (int j = 0; j < 6; ++j) {
        const int colbase = rj[j] * 128;
        // Batch all 16 HBM loads for this region up-front (latency overlap):
        // lane reads 8 consecutive fp32 per (mt,kk): A[m=s][k=q*8+i]
        float4 rawA[2][4][2];
#pragma unroll
        for (int mt = 0; mt < 2; ++mt) {
            const float* rowp =
                spikes + (size_t)(tok0 + mt * 16 + s) * 1024 + colbase + q * 8;
#pragma unroll
            for (int kk = 0; kk < 4; ++kk) {
                rawA[mt][kk][0] = *(const float4*)(rowp + kk * 32);
                rawA[mt][kk][1] = *(const float4*)(rowp + kk * 32 + 4);
            }
        }
#pragma unroll
        for (int kk = 0; kk < 4; ++kk) {
            const int col = colbase + kk * 32 + q * 8;
            // B fragments from L2-hot F: B[n=s][k=q*8+i], 16B contiguous
            bf16x8 bf[10];
#pragma unroll
            for (int nt = 0; nt < 10; ++nt)
                bf[nt] = *(const bf16x8*)(F + (size_t)(nt * 16 + s) * 1024 + col);
#pragma unroll
            for (int mt = 0; mt < 2; ++mt) {
                const float4 lo = rawA[mt][kk][0];
                const float4 hi = rawA[mt][kk][1];
                bf16x8 af;
                af[0] = (__bf16)lo.x; af[1] = (__bf16)lo.y;
                af[2] = (__bf16)lo.z; af[3] = (__bf16)lo.w;
                af[4] = (__bf16)hi.x; af[5] = (__bf16)hi.y;
                af[6] = (__bf16)hi.z; af[7] = (__bf16)hi.w;
#pragma unroll
                for (int nt = 0; nt < 10; ++nt)
                    acc[mt][nt] = __builtin_amdgcn_mfma_f32_16x16x32_bf16(
                        af, bf[nt], acc[mt][nt], 0, 0, 0);
            }
        }
    }

    // Epilogue: D[row=q*4+i][col=s]; token = tok0 + mt*16 + q*4 + i, l = nt*16 + s
#pragma unroll
    for (int nt = 0; nt < 10; ++nt) {
        const int l = nt * 16 + s;
        float bias = bias0[l];
#pragma unroll
        for (int j = 0; j < 6; ++j) bias += bias_area[l * 8 + rj[j]];
#pragma unroll
        for (int mt = 0; mt < 2; ++mt) {
            const int tk = tok0 + mt * 16 + q * 4;
#pragma unroll
            for (int i = 0; i < 4; ++i)
                out[(size_t)(tk + i) * 160 + l] = acc[mt][nt][i] + bias;
        }
    }
}

extern "C" void kernel_launch(void* const* d_in, const int* in_sizes, int n_in,
                              void* d_out, int out_size, void* d_ws, size_t ws_size,
                              hipStream_t stream) {
    (void)in_sizes; (void)n_in; (void)out_size; (void)ws_size;
    const float* spikes = (const float*)d_in[0];  // (32,1024,1024)
    const float* W_area = (const float*)d_in[1];  // (8,32,128)
    const float* b_area = (const float*)d_in[2];  // (8,32)
    const float* U_W    = (const float*)d_in[3];  // (1024,256)
    const float* U_b    = (const float*)d_in[4];  // (1024,)
    const float* V_W    = (const float*)d_in[5];  // (160,1024)
    const float* V_b    = (const float*)d_in[6];  // (160,)
    const int*   ids    = (const int*)d_in[7];    // (32,8) int32
    float* out = (float*)d_out;                   // (32,1024,160) fp32

    char* ws = (char*)d_ws;
    float*  M_part    = (float*)ws;               // [4][160][256] fp32 = 655360 B
    __bf16* F         = (__bf16*)(ws + 655360);   // [160][1024] bf16 = 327680 B
    float*  bias_area = (float*)(ws + 983040);    // [160][8] fp32   = 5120 B
    float*  bias0     = (float*)(ws + 988160);    // [160] fp32      = 640 B

    pa_kernel<<<160, 256, 0, stream>>>(V_W, U_W, M_part);
    pb_kernel<<<160, 256, 0, stream>>>(M_part, W_area, b_area, V_W, U_b, V_b,
                                       F, bias_area, bias0);
    main_kernel<<<256, 256, 0, stream>>>(spikes, ids, F, bias_area, bias0, out);
}